// Round 1
// baseline (439.582 us; speedup 1.0000x reference)
//
#include <hip/hip_runtime.h>

#define B 2
#define N 20000
#define M 4096
#define S 2
#define K 25
#define J 64
#define CIN 8
#define COUT 64
#define KJ (K*J)        // 1600
#define PITCH 66        // pad k-rows: bank = (2k + j) % 32 -> distinct per k in a wave
#define TC 32           // MLP column tile

// ---------------- Kernel A: prep (xf build, conv_w transpose, new_xyz copy) ----------------
__global__ __launch_bounds__(256) void prep_kernel(
    const float* __restrict__ xyz, const float* __restrict__ feature,
    const float* __restrict__ new_xyz, const float* __restrict__ conv_w,
    float* __restrict__ xf, float* __restrict__ conv_wT, float* __restrict__ out_newxyz) {
    const int T1 = B * N * CIN;   // 320000
    const int T2 = 200 * 64;      // 12800
    const int T3 = B * M * 3;     // 24576
    int e = blockIdx.x * blockDim.x + threadIdx.x;
    if (e < T1) {
        int r = e >> 3, t = e & 7;
        xf[e] = (t < 2) ? xyz[r * 3 + t] : feature[r * 6 + (t - 2)];
    } else if (e < T1 + T2) {
        int e2 = e - T1;
        int i = e2 >> 6, o = e2 & 63;           // i = k*8+c
        conv_wT[e2] = conv_w[o * 200 + (i & 7) * 25 + (i >> 3)];
    } else if (e < T1 + T2 + T3) {
        int e3 = e - T1 - T2;
        out_newxyz[e3] = new_xyz[e3];
    }
}

// ---------------- Kernel B: gather + weighted sum + center sub + conv + relu ----------------
__global__ __launch_bounds__(256) void gather_conv_kernel(
    const int* __restrict__ idx, const float* __restrict__ weight,
    const float* __restrict__ new_xyz, const float* __restrict__ xf,
    const float* __restrict__ conv_wT, const float* __restrict__ conv_b,
    float* __restrict__ xmid) {
    __shared__ int   sidx[K * PITCH];
    __shared__ float sw[K * PITCH];
    __shared__ float snf[200];
    __shared__ float spart[4][64];
    __shared__ float scent[2];

    int g = blockIdx.x;               // g = (s*B + b)*M + m
    int m = g & (M - 1);
    int sb = g >> 12;                 // g / M
    int b = sb & (B - 1);
    int s = sb >> 1;
    int tid = threadIdx.x;

    const int*   gi = idx    + (size_t)g * KJ;
    const float* gw = weight + (size_t)g * KJ;
    for (int t = tid; t < KJ; t += 256) {
        int k = t >> 6, j = t & 63;
        sidx[k * PITCH + j] = gi[t];
        sw[k * PITCH + j]   = gw[t];
    }
    if (tid < 2) scent[tid] = new_xyz[(b * M + m) * 3 + tid];
    __syncthreads();

    if (tid < 200) {
        int k = tid >> 3, c = tid & 7;
        const float* xfb = xf + b * (N * CIN) + c;
        const int*   si  = sidx + k * PITCH;
        const float* swk = sw   + k * PITCH;
        float acc = 0.f;
        #pragma unroll 8
        for (int j = 0; j < J; ++j) {
            acc = fmaf(swk[j], xfb[si[j] * CIN], acc);
        }
        if (c < 2) acc -= scent[c];
        snf[tid] = acc;               // tid == k*8+c == i
    }
    __syncthreads();

    int o = tid & 63, part = tid >> 6;
    float acc = 0.f;
    int i0 = part * 50;
    #pragma unroll
    for (int i = i0; i < i0 + 50; ++i)
        acc = fmaf(snf[i], conv_wT[i * 64 + o], acc);
    spart[part][o] = acc;
    __syncthreads();

    if (tid < 64) {
        float v = spart[0][tid] + spart[1][tid] + spart[2][tid] + spart[3][tid] + conv_b[tid];
        v = fmaxf(v, 0.f);
        xmid[((size_t)b * 128 + s * 64 + tid) * M + m] = v;
    }
}

// ---------------- Kernel C: MLP0+relu, MLP1+relu, transpose store ----------------
__global__ __launch_bounds__(256) void mlp_kernel(
    const float* __restrict__ xmid,
    const float* __restrict__ w0, const float* __restrict__ b0,
    const float* __restrict__ w1, const float* __restrict__ b1,
    float* __restrict__ out_rf) {
    __shared__ float xs[128 * TC];
    __shared__ float ys0[128 * TC];
    __shared__ float ys1[TC * 257];

    int tid = threadIdx.x;
    int col0 = blockIdx.x * TC;           // global col: b*M + m
    int b = col0 / M;                     // uniform across block (TC divides M)
    int m0 = col0 - b * M;

    for (int r = tid; r < 128 * TC; r += 256) {
        int c = r >> 5, lc = r & 31;
        xs[r] = xmid[((size_t)b * 128 + c) * M + m0 + lc];
    }
    __syncthreads();

    int col = tid & 31, og = tid >> 5;    // og in 0..7
    {
        float acc[16];
        #pragma unroll
        for (int i = 0; i < 16; ++i) acc[i] = b0[og * 16 + i];
        for (int c = 0; c < 128; ++c) {
            float xv = xs[c * TC + col];
            #pragma unroll
            for (int i = 0; i < 16; ++i)
                acc[i] = fmaf(w0[(og * 16 + i) * 128 + c], xv, acc[i]);
        }
        #pragma unroll
        for (int i = 0; i < 16; ++i)
            ys0[(og * 16 + i) * TC + col] = fmaxf(acc[i], 0.f);
    }
    __syncthreads();
    {
        float acc[32];
        #pragma unroll
        for (int i = 0; i < 32; ++i) acc[i] = b1[og * 32 + i];
        for (int c = 0; c < 128; ++c) {
            float yv = ys0[c * TC + col];
            #pragma unroll
            for (int i = 0; i < 32; ++i)
                acc[i] = fmaf(w1[(og * 32 + i) * 128 + c], yv, acc[i]);
        }
        #pragma unroll
        for (int i = 0; i < 32; ++i)
            ys1[col * 257 + og * 32 + i] = fmaxf(acc[i], 0.f);
    }
    __syncthreads();
    for (int cc = 0; cc < TC; ++cc) {
        out_rf[(size_t)(col0 + cc) * 256 + tid] = ys1[cc * 257 + tid];
    }
}

extern "C" void kernel_launch(void* const* d_in, const int* in_sizes, int n_in,
                              void* d_out, int out_size, void* d_ws, size_t ws_size,
                              hipStream_t stream) {
    const float* xyz     = (const float*)d_in[0];
    const float* feature = (const float*)d_in[1];
    const float* new_xyz = (const float*)d_in[2];
    const int*   idx     = (const int*)  d_in[3];
    const float* weight  = (const float*)d_in[4];
    const float* conv_w  = (const float*)d_in[5];
    const float* conv_b  = (const float*)d_in[6];
    const float* mlp_w0  = (const float*)d_in[7];
    const float* mlp_b0  = (const float*)d_in[8];
    const float* mlp_w1  = (const float*)d_in[9];
    const float* mlp_b1  = (const float*)d_in[10];

    float* out    = (float*)d_out;
    float* out_rf = out + (size_t)B * M * 3;

    float* xf      = (float*)d_ws;              // 320000 floats
    float* conv_wT = xf + 320000;               // 12800 floats
    float* xmid    = conv_wT + 12800;           // B*128*M = 1048576 floats

    // A: prep
    {
        int total = B * N * CIN + 200 * 64 + B * M * 3;   // 357376
        int blocks = (total + 255) / 256;
        prep_kernel<<<blocks, 256, 0, stream>>>(xyz, feature, new_xyz, conv_w,
                                                xf, conv_wT, out);
    }
    // B: gather + conv
    {
        int blocks = S * B * M;                 // 16384
        gather_conv_kernel<<<blocks, 256, 0, stream>>>(idx, weight, new_xyz, xf,
                                                       conv_wT, conv_b, xmid);
    }
    // C: MLPs + transpose out
    {
        int blocks = (B * M) / TC;              // 256
        mlp_kernel<<<blocks, 256, 0, stream>>>(xmid, mlp_w0, mlp_b0, mlp_w1, mlp_b1,
                                               out_rf);
    }
}

// Round 2
// 387.319 us; speedup vs baseline: 1.1349x; 1.1349x over previous
//
#include <hip/hip_runtime.h>

#define B 2
#define N 20000
#define M 4096
#define S 2
#define K 25
#define J 64
#define CIN 8
#define KJ (K*J)        // 1600
#define TC 32           // MLP column tile
#define XP 36           // LDS pitch for [c][col] tiles (16B-aligned, conflict-free b128)

// ---------------- Kernel A: prep ----------------
// xf build, conv_w transpose (padded to 208 rows), new_xyz copy, w0/w1 transpose
__global__ __launch_bounds__(256) void prep_kernel(
    const float* __restrict__ xyz, const float* __restrict__ feature,
    const float* __restrict__ new_xyz, const float* __restrict__ conv_w,
    const float* __restrict__ w0, const float* __restrict__ w1,
    float* __restrict__ xf, float* __restrict__ conv_wT,
    float* __restrict__ w0T, float* __restrict__ w1T,
    float* __restrict__ out_newxyz) {
    const int T1 = B * N * CIN;   // 320000
    const int T2 = 208 * 64;      // 13312
    const int T3 = B * M * 3;     // 24576
    const int T4 = 128 * 128;     // 16384
    const int T5 = 128 * 256;     // 32768
    int e = blockIdx.x * blockDim.x + threadIdx.x;
    if (e < T1) {
        int r = e >> 3, t = e & 7;
        xf[e] = (t < 2) ? xyz[r * 3 + t] : feature[r * 6 + (t - 2)];
    } else if (e < T1 + T2) {
        int e2 = e - T1;
        int i = e2 >> 6, o = e2 & 63;           // i = k*8+c
        conv_wT[e2] = (i < 200) ? conv_w[o * 200 + (i & 7) * 25 + (i >> 3)] : 0.f;
    } else if (e < T1 + T2 + T3) {
        int e3 = e - T1 - T2;
        out_newxyz[e3] = new_xyz[e3];
    } else if (e < T1 + T2 + T3 + T4) {
        int e4 = e - T1 - T2 - T3;
        int c = e4 >> 7, o = e4 & 127;          // w0T[c][o]
        w0T[e4] = w0[o * 128 + c];
    } else if (e < T1 + T2 + T3 + T4 + T5) {
        int e5 = e - T1 - T2 - T3 - T4;
        int c = e5 >> 8, o = e5 & 255;          // w1T[c][o]
        w1T[e5] = w1[o * 128 + c];
    }
}

// ---------------- Kernel B: gather + weighted sum + center sub + conv + relu ----------------
__global__ __launch_bounds__(256) void gather_conv_kernel(
    const int* __restrict__ idx, const float* __restrict__ weight,
    const float* __restrict__ new_xyz, const float* __restrict__ xf,
    const float* __restrict__ conv_wT, const float* __restrict__ conv_b,
    float* __restrict__ xmid) {
    __shared__ float snf[208];
    __shared__ float spart[4][64];

    int g = blockIdx.x;               // g = (s*B + b)*M + m
    int m = g & (M - 1);
    int sb = g >> 12;
    int b = sb & (B - 1);
    int s = sb >> 1;
    int tid = threadIdx.x;

    if (tid >= 200 && tid < 208) snf[tid] = 0.f;

    if (tid < 200) {
        int k = tid >> 3, jg = tid & 7;
        (void)k;
        const int4*   gi4 = (const int4*)  (idx    + (size_t)g * KJ);
        const float4* gw4 = (const float4*)(weight + (size_t)g * KJ);
        int4   ia = gi4[tid * 2], ib = gi4[tid * 2 + 1];
        float4 wa = gw4[tid * 2], wb = gw4[tid * 2 + 1];

        const float4* xfb = (const float4*)(xf + (size_t)b * N * CIN);
        float acc[8] = {0.f,0.f,0.f,0.f,0.f,0.f,0.f,0.f};
        int   rows[8] = {ia.x, ia.y, ia.z, ia.w, ib.x, ib.y, ib.z, ib.w};
        float wsv[8]  = {wa.x, wa.y, wa.z, wa.w, wb.x, wb.y, wb.z, wb.w};
        #pragma unroll
        for (int j = 0; j < 8; ++j) {
            float4 lo = xfb[rows[j] * 2];
            float4 hi = xfb[rows[j] * 2 + 1];
            float w = wsv[j];
            acc[0] = fmaf(w, lo.x, acc[0]);
            acc[1] = fmaf(w, lo.y, acc[1]);
            acc[2] = fmaf(w, lo.z, acc[2]);
            acc[3] = fmaf(w, lo.w, acc[3]);
            acc[4] = fmaf(w, hi.x, acc[4]);
            acc[5] = fmaf(w, hi.y, acc[5]);
            acc[6] = fmaf(w, hi.z, acc[6]);
            acc[7] = fmaf(w, hi.w, acc[7]);
        }
        // reduce across the 8 jg lanes (contiguous within a wave)
        #pragma unroll
        for (int d = 1; d < 8; d <<= 1) {
            #pragma unroll
            for (int c = 0; c < 8; ++c) acc[c] += __shfl_xor(acc[c], d, 64);
        }
        if (jg == 0) {
            int kk = tid >> 3;
            float cx = new_xyz[(b * M + m) * 3 + 0];
            float cy = new_xyz[(b * M + m) * 3 + 1];
            acc[0] -= cx; acc[1] -= cy;
            float4* s4 = (float4*)&snf[kk * 8];
            s4[0] = make_float4(acc[0], acc[1], acc[2], acc[3]);
            s4[1] = make_float4(acc[4], acc[5], acc[6], acc[7]);
        }
    }
    __syncthreads();

    // conv: 256 threads = 64 o x 4 parts, each part covers 52 i (padded with zeros)
    int o = tid & 63, p = tid >> 6;
    const float4* snf4 = (const float4*)snf;
    float acc2 = 0.f;
    #pragma unroll
    for (int q = 0; q < 13; ++q) {
        float4 v = snf4[p * 13 + q];
        int i = (p * 13 + q) * 4;
        acc2 = fmaf(v.x, conv_wT[(i + 0) * 64 + o], acc2);
        acc2 = fmaf(v.y, conv_wT[(i + 1) * 64 + o], acc2);
        acc2 = fmaf(v.z, conv_wT[(i + 2) * 64 + o], acc2);
        acc2 = fmaf(v.w, conv_wT[(i + 3) * 64 + o], acc2);
    }
    spart[p][o] = acc2;
    __syncthreads();

    if (tid < 64) {
        float v = spart[0][tid] + spart[1][tid] + spart[2][tid] + spart[3][tid] + conv_b[tid];
        v = fmaxf(v, 0.f);
        // xmid layout: [b*M+m][128] -> coalesced 256B store per block
        xmid[((size_t)(b * M + m)) * 128 + s * 64 + tid] = v;
    }
}

// ---------------- Kernel C: MLP0+relu, MLP1+relu, store ----------------
__global__ __launch_bounds__(256) void mlp_kernel(
    const float* __restrict__ xmid,
    const float* __restrict__ w0T, const float* __restrict__ b0,
    const float* __restrict__ w1T, const float* __restrict__ b1,
    float* __restrict__ out_rf) {
    __shared__ float xs[128 * XP];    // [c][col]
    __shared__ float ys0[128 * XP];   // [c][col]

    int tid = threadIdx.x;
    int col0 = blockIdx.x * TC;           // global col: b*M + m

    // load x tile: xmid is [col][128]
    {
        const float4* xm4 = (const float4*)(xmid + (size_t)col0 * 128);
        #pragma unroll
        for (int r = tid; r < 32 * TC; r += 256) {
            int lc = r >> 5, c4 = r & 31;
            float4 v = xm4[lc * 32 + c4];
            int c = c4 * 4;
            xs[(c + 0) * XP + lc] = v.x;
            xs[(c + 1) * XP + lc] = v.y;
            xs[(c + 2) * XP + lc] = v.z;
            xs[(c + 3) * XP + lc] = v.w;
        }
    }
    __syncthreads();

    // MLP0: 128 outputs. 256 thr = 32 ogroups(4 o) x 8 colgroups(4 col)
    {
        int og = tid >> 3, cg = tid & 7;
        int o0 = og * 4, lc0 = cg * 4;
        float acc[4][4];
        #pragma unroll
        for (int i = 0; i < 4; ++i) {
            float bv = b0[o0 + i];
            #pragma unroll
            for (int u = 0; u < 4; ++u) acc[i][u] = bv;
        }
        for (int c = 0; c < 128; ++c) {
            float4 xv = *(const float4*)&xs[c * XP + lc0];
            float4 wv = *(const float4*)&w0T[c * 128 + o0];
            acc[0][0] = fmaf(wv.x, xv.x, acc[0][0]);
            acc[0][1] = fmaf(wv.x, xv.y, acc[0][1]);
            acc[0][2] = fmaf(wv.x, xv.z, acc[0][2]);
            acc[0][3] = fmaf(wv.x, xv.w, acc[0][3]);
            acc[1][0] = fmaf(wv.y, xv.x, acc[1][0]);
            acc[1][1] = fmaf(wv.y, xv.y, acc[1][1]);
            acc[1][2] = fmaf(wv.y, xv.z, acc[1][2]);
            acc[1][3] = fmaf(wv.y, xv.w, acc[1][3]);
            acc[2][0] = fmaf(wv.z, xv.x, acc[2][0]);
            acc[2][1] = fmaf(wv.z, xv.y, acc[2][1]);
            acc[2][2] = fmaf(wv.z, xv.z, acc[2][2]);
            acc[2][3] = fmaf(wv.z, xv.w, acc[2][3]);
            acc[3][0] = fmaf(wv.w, xv.x, acc[3][0]);
            acc[3][1] = fmaf(wv.w, xv.y, acc[3][1]);
            acc[3][2] = fmaf(wv.w, xv.z, acc[3][2]);
            acc[3][3] = fmaf(wv.w, xv.w, acc[3][3]);
        }
        #pragma unroll
        for (int i = 0; i < 4; ++i)
            #pragma unroll
            for (int u = 0; u < 4; ++u)
                ys0[(o0 + i) * XP + lc0 + u] = fmaxf(acc[i][u], 0.f);
    }
    __syncthreads();

    // MLP1: 256 outputs. 256 thr = 64 ogroups(4 o) x 4 colgroups(8 col)
    {
        int og = tid >> 2, cg = tid & 3;
        int o0 = og * 4, lc0 = cg * 8;
        float acc[4][8];
        #pragma unroll
        for (int i = 0; i < 4; ++i) {
            float bv = b1[o0 + i];
            #pragma unroll
            for (int u = 0; u < 8; ++u) acc[i][u] = bv;
        }
        for (int c = 0; c < 128; ++c) {
            float4 xa = *(const float4*)&ys0[c * XP + lc0];
            float4 xb = *(const float4*)&ys0[c * XP + lc0 + 4];
            float4 wv = *(const float4*)&w1T[c * 256 + o0];
            float xv[8] = {xa.x, xa.y, xa.z, xa.w, xb.x, xb.y, xb.z, xb.w};
            #pragma unroll
            for (int i = 0; i < 4; ++i) {
                float w = (i == 0) ? wv.x : (i == 1) ? wv.y : (i == 2) ? wv.z : wv.w;
                #pragma unroll
                for (int u = 0; u < 8; ++u)
                    acc[i][u] = fmaf(w, xv[u], acc[i][u]);
            }
        }
        #pragma unroll
        for (int u = 0; u < 8; ++u) {
            float4 v = make_float4(fmaxf(acc[0][u], 0.f), fmaxf(acc[1][u], 0.f),
                                   fmaxf(acc[2][u], 0.f), fmaxf(acc[3][u], 0.f));
            *(float4*)&out_rf[(size_t)(col0 + lc0 + u) * 256 + o0] = v;
        }
    }
}

extern "C" void kernel_launch(void* const* d_in, const int* in_sizes, int n_in,
                              void* d_out, int out_size, void* d_ws, size_t ws_size,
                              hipStream_t stream) {
    const float* xyz     = (const float*)d_in[0];
    const float* feature = (const float*)d_in[1];
    const float* new_xyz = (const float*)d_in[2];
    const int*   idx     = (const int*)  d_in[3];
    const float* weight  = (const float*)d_in[4];
    const float* conv_w  = (const float*)d_in[5];
    const float* conv_b  = (const float*)d_in[6];
    const float* mlp_w0  = (const float*)d_in[7];
    const float* mlp_b0  = (const float*)d_in[8];
    const float* mlp_w1  = (const float*)d_in[9];
    const float* mlp_b1  = (const float*)d_in[10];

    float* out    = (float*)d_out;
    float* out_rf = out + (size_t)B * M * 3;

    float* xf      = (float*)d_ws;              // 320000
    float* conv_wT = xf + 320000;               // 13312 (208x64, zero-padded)
    float* xmid    = conv_wT + 13312;           // B*M*128 = 1048576, [col][c] layout
    float* w0T     = xmid + 1048576;            // 16384
    float* w1T     = w0T + 16384;               // 32768

    // A: prep
    {
        int total = 320000 + 13312 + 24576 + 16384 + 32768;   // 407040
        int blocks = (total + 255) / 256;
        prep_kernel<<<blocks, 256, 0, stream>>>(xyz, feature, new_xyz, conv_w,
                                                mlp_w0, mlp_w1,
                                                xf, conv_wT, w0T, w1T, out);
    }
    // B: gather + conv
    {
        int blocks = S * B * M;                 // 16384
        gather_conv_kernel<<<blocks, 256, 0, stream>>>(idx, weight, new_xyz, xf,
                                                       conv_wT, conv_b, xmid);
    }
    // C: MLPs + store
    {
        int blocks = (B * M) / TC;              // 256
        mlp_kernel<<<blocks, 256, 0, stream>>>(xmid, w0T, mlp_b0, w1T, mlp_b1,
                                               out_rf);
    }
}

// Round 3
// 384.625 us; speedup vs baseline: 1.1429x; 1.0070x over previous
//
#include <hip/hip_runtime.h>
#include <hip/hip_bf16.h>

#define B 2
#define N 20000
#define M 4096
#define S 2
#define K 25
#define J 64
#define KJ (K*J)        // 1600
#define TC 32           // MLP column tile
#define XP 36           // LDS pitch for [c][col] tiles (16B-aligned, conflict-free b128)

typedef unsigned int u32;

// ---------------- Kernel A: prep ----------------
// xfh bf16 build (16B rows), conv_w transpose (padded 208 rows), new_xyz copy, w0/w1 transpose
__global__ __launch_bounds__(256) void prep_kernel(
    const float* __restrict__ xyz, const float* __restrict__ feature,
    const float* __restrict__ new_xyz, const float* __restrict__ conv_w,
    const float* __restrict__ w0, const float* __restrict__ w1,
    __hip_bfloat16* __restrict__ xfh, float* __restrict__ conv_wT,
    float* __restrict__ w0T, float* __restrict__ w1T,
    float* __restrict__ out_newxyz) {
    const int T1 = B * N * 8;     // 320000
    const int T2 = 208 * 64;      // 13312
    const int T3 = B * M * 3;     // 24576
    const int T4 = 128 * 128;     // 16384
    const int T5 = 128 * 256;     // 32768
    int e = blockIdx.x * blockDim.x + threadIdx.x;
    if (e < T1) {
        int r = e >> 3, t = e & 7;
        float v = (t < 2) ? xyz[r * 3 + t] : feature[r * 6 + (t - 2)];
        xfh[e] = __float2bfloat16(v);
    } else if (e < T1 + T2) {
        int e2 = e - T1;
        int i = e2 >> 6, o = e2 & 63;           // i = k*8+c
        conv_wT[e2] = (i < 200) ? conv_w[o * 200 + (i & 7) * 25 + (i >> 3)] : 0.f;
    } else if (e < T1 + T2 + T3) {
        int e3 = e - T1 - T2;
        out_newxyz[e3] = new_xyz[e3];
    } else if (e < T1 + T2 + T3 + T4) {
        int e4 = e - T1 - T2 - T3;
        int c = e4 >> 7, o = e4 & 127;          // w0T[c][o]
        w0T[e4] = w0[o * 128 + c];
    } else if (e < T1 + T2 + T3 + T4 + T5) {
        int e5 = e - T1 - T2 - T3 - T4;
        int c = e5 >> 8, o = e5 & 255;          // w1T[c][o]
        w1T[e5] = w1[o * 128 + c];
    }
}

// ---------------- Kernel B: gather (bf16 rows) + weighted sum + center sub + conv + relu ----
__global__ __launch_bounds__(256) void gather_conv_kernel(
    const int* __restrict__ idx, const float* __restrict__ weight,
    const float* __restrict__ new_xyz, const uint4* __restrict__ xfh,
    const float* __restrict__ conv_wT, const float* __restrict__ conv_b,
    float* __restrict__ xmid) {
    __shared__ float snf[208];
    __shared__ float spart[4][64];

    int g = blockIdx.x;               // g = (s*B + b)*M + m
    int m = g & (M - 1);
    int sb = g >> 12;
    int b = sb & (B - 1);
    int s = sb >> 1;
    int tid = threadIdx.x;

    if (tid >= 200 && tid < 208) snf[tid] = 0.f;

    if (tid < 200) {
        const int4*   gi4 = (const int4*)  (idx    + (size_t)g * KJ);
        const float4* gw4 = (const float4*)(weight + (size_t)g * KJ);
        int4   ia = gi4[tid * 2], ib = gi4[tid * 2 + 1];
        float4 wa = gw4[tid * 2], wb = gw4[tid * 2 + 1];

        const uint4* xfb = xfh + (size_t)b * N;   // one 16B row per point
        float acc[8] = {0.f,0.f,0.f,0.f,0.f,0.f,0.f,0.f};
        int   rows[8] = {ia.x, ia.y, ia.z, ia.w, ib.x, ib.y, ib.z, ib.w};
        float wsv[8]  = {wa.x, wa.y, wa.z, wa.w, wb.x, wb.y, wb.z, wb.w};
        #pragma unroll
        for (int j = 0; j < 8; ++j) {
            uint4 r = xfb[rows[j]];
            float w = wsv[j];
            acc[0] = fmaf(w, __uint_as_float(r.x << 16),          acc[0]);
            acc[1] = fmaf(w, __uint_as_float(r.x & 0xffff0000u),  acc[1]);
            acc[2] = fmaf(w, __uint_as_float(r.y << 16),          acc[2]);
            acc[3] = fmaf(w, __uint_as_float(r.y & 0xffff0000u),  acc[3]);
            acc[4] = fmaf(w, __uint_as_float(r.z << 16),          acc[4]);
            acc[5] = fmaf(w, __uint_as_float(r.z & 0xffff0000u),  acc[5]);
            acc[6] = fmaf(w, __uint_as_float(r.w << 16),          acc[6]);
            acc[7] = fmaf(w, __uint_as_float(r.w & 0xffff0000u),  acc[7]);
        }
        // reduce across the 8 jg lanes (contiguous within a wave)
        #pragma unroll
        for (int d = 1; d < 8; d <<= 1) {
            #pragma unroll
            for (int c = 0; c < 8; ++c) acc[c] += __shfl_xor(acc[c], d, 64);
        }
        if ((tid & 7) == 0) {
            int kk = tid >> 3;
            float cx = new_xyz[(b * M + m) * 3 + 0];
            float cy = new_xyz[(b * M + m) * 3 + 1];
            acc[0] -= cx; acc[1] -= cy;
            float4* s4 = (float4*)&snf[kk * 8];
            s4[0] = make_float4(acc[0], acc[1], acc[2], acc[3]);
            s4[1] = make_float4(acc[4], acc[5], acc[6], acc[7]);
        }
    }
    __syncthreads();

    // conv: 256 threads = 64 o x 4 parts, each part covers 52 i (zero-padded)
    int o = tid & 63, p = tid >> 6;
    const float4* snf4 = (const float4*)snf;
    float acc2 = 0.f;
    #pragma unroll
    for (int q = 0; q < 13; ++q) {
        float4 v = snf4[p * 13 + q];
        int i = (p * 13 + q) * 4;
        acc2 = fmaf(v.x, conv_wT[(i + 0) * 64 + o], acc2);
        acc2 = fmaf(v.y, conv_wT[(i + 1) * 64 + o], acc2);
        acc2 = fmaf(v.z, conv_wT[(i + 2) * 64 + o], acc2);
        acc2 = fmaf(v.w, conv_wT[(i + 3) * 64 + o], acc2);
    }
    spart[p][o] = acc2;
    __syncthreads();

    if (tid < 64) {
        float v = spart[0][tid] + spart[1][tid] + spart[2][tid] + spart[3][tid] + conv_b[tid];
        v = fmaxf(v, 0.f);
        xmid[((size_t)(b * M + m)) * 128 + s * 64 + tid] = v;   // [col][c], coalesced
    }
}

// ---------------- Kernel C0: MLP0 + relu (in-place xmid [col][128]) ----------------
__global__ __launch_bounds__(256) void mlp0_kernel(
    float* __restrict__ xmid,
    const float* __restrict__ w0T, const float* __restrict__ b0) {
    __shared__ float ws[128 * 128];   // 64 KB, [c][o]
    __shared__ float xs[128 * XP];    // 18 KB, [c][col]

    int tid = threadIdx.x;
    int col0 = blockIdx.x * TC;

    {   // stage weights: 4096 float4
        const float4* w4 = (const float4*)w0T;
        float4* ws4 = (float4*)ws;
        #pragma unroll
        for (int i = 0; i < 16; ++i) ws4[tid + 256 * i] = w4[tid + 256 * i];
    }
    {   // stage x tile (xmid is [col][128])
        const float4* xm4 = (const float4*)(xmid + (size_t)col0 * 128);
        #pragma unroll
        for (int r = tid; r < 32 * TC; r += 256) {
            int lc = r >> 5, c4 = r & 31;
            float4 v = xm4[lc * 32 + c4];
            int c = c4 * 4;
            xs[(c + 0) * XP + lc] = v.x;
            xs[(c + 1) * XP + lc] = v.y;
            xs[(c + 2) * XP + lc] = v.z;
            xs[(c + 3) * XP + lc] = v.w;
        }
    }
    __syncthreads();

    int og = tid >> 3, cg = tid & 7;
    int o0 = og * 4, lc0 = cg * 4;
    float acc[4][4];
    #pragma unroll
    for (int i = 0; i < 4; ++i) {
        float bv = b0[o0 + i];
        #pragma unroll
        for (int u = 0; u < 4; ++u) acc[i][u] = bv;
    }
    for (int c = 0; c < 128; ++c) {
        float4 xv = *(const float4*)&xs[c * XP + lc0];
        float4 wv = *(const float4*)&ws[c * 128 + o0];
        acc[0][0] = fmaf(wv.x, xv.x, acc[0][0]);
        acc[0][1] = fmaf(wv.x, xv.y, acc[0][1]);
        acc[0][2] = fmaf(wv.x, xv.z, acc[0][2]);
        acc[0][3] = fmaf(wv.x, xv.w, acc[0][3]);
        acc[1][0] = fmaf(wv.y, xv.x, acc[1][0]);
        acc[1][1] = fmaf(wv.y, xv.y, acc[1][1]);
        acc[1][2] = fmaf(wv.y, xv.z, acc[1][2]);
        acc[1][3] = fmaf(wv.y, xv.w, acc[1][3]);
        acc[2][0] = fmaf(wv.z, xv.x, acc[2][0]);
        acc[2][1] = fmaf(wv.z, xv.y, acc[2][1]);
        acc[2][2] = fmaf(wv.z, xv.z, acc[2][2]);
        acc[2][3] = fmaf(wv.z, xv.w, acc[2][3]);
        acc[3][0] = fmaf(wv.w, xv.x, acc[3][0]);
        acc[3][1] = fmaf(wv.w, xv.y, acc[3][1]);
        acc[3][2] = fmaf(wv.w, xv.z, acc[3][2]);
        acc[3][3] = fmaf(wv.w, xv.w, acc[3][3]);
    }
    // in-place write-back, [col][128] (tile fully consumed into LDS above)
    #pragma unroll
    for (int u = 0; u < 4; ++u) {
        float4 v = make_float4(fmaxf(acc[0][u], 0.f), fmaxf(acc[1][u], 0.f),
                               fmaxf(acc[2][u], 0.f), fmaxf(acc[3][u], 0.f));
        *(float4*)&xmid[(size_t)(col0 + lc0 + u) * 128 + o0] = v;
    }
}

// ---------------- Kernel C1: MLP1 + relu + store ----------------
__global__ __launch_bounds__(256) void mlp1_kernel(
    const float* __restrict__ xmid,
    const float* __restrict__ w1T, const float* __restrict__ b1,
    float* __restrict__ out_rf) {
    __shared__ float ws[128 * 256];   // 128 KB, [c][o]
    __shared__ float xs[128 * XP];    // 18 KB -> 146 KB total (<=160)

    int tid = threadIdx.x;
    int col0 = blockIdx.x * TC;

    {   // stage weights: 8192 float4
        const float4* w4 = (const float4*)w1T;
        float4* ws4 = (float4*)ws;
        #pragma unroll
        for (int i = 0; i < 32; ++i) ws4[tid + 256 * i] = w4[tid + 256 * i];
    }
    {   // stage y0 tile
        const float4* xm4 = (const float4*)(xmid + (size_t)col0 * 128);
        #pragma unroll
        for (int r = tid; r < 32 * TC; r += 256) {
            int lc = r >> 5, c4 = r & 31;
            float4 v = xm4[lc * 32 + c4];
            int c = c4 * 4;
            xs[(c + 0) * XP + lc] = v.x;
            xs[(c + 1) * XP + lc] = v.y;
            xs[(c + 2) * XP + lc] = v.z;
            xs[(c + 3) * XP + lc] = v.w;
        }
    }
    __syncthreads();

    int og = tid >> 2, cg = tid & 3;
    int o0 = og * 4, lc0 = cg * 8;
    float acc[4][8];
    #pragma unroll
    for (int i = 0; i < 4; ++i) {
        float bv = b1[o0 + i];
        #pragma unroll
        for (int u = 0; u < 8; ++u) acc[i][u] = bv;
    }
    for (int c = 0; c < 128; ++c) {
        float4 xa = *(const float4*)&xs[c * XP + lc0];
        float4 xb = *(const float4*)&xs[c * XP + lc0 + 4];
        float4 wv = *(const float4*)&ws[c * 256 + o0];
        float xv[8] = {xa.x, xa.y, xa.z, xa.w, xb.x, xb.y, xb.z, xb.w};
        #pragma unroll
        for (int u = 0; u < 8; ++u) {
            acc[0][u] = fmaf(wv.x, xv[u], acc[0][u]);
            acc[1][u] = fmaf(wv.y, xv[u], acc[1][u]);
            acc[2][u] = fmaf(wv.z, xv[u], acc[2][u]);
            acc[3][u] = fmaf(wv.w, xv[u], acc[3][u]);
        }
    }
    #pragma unroll
    for (int u = 0; u < 8; ++u) {
        float4 v = make_float4(fmaxf(acc[0][u], 0.f), fmaxf(acc[1][u], 0.f),
                               fmaxf(acc[2][u], 0.f), fmaxf(acc[3][u], 0.f));
        *(float4*)&out_rf[(size_t)(col0 + lc0 + u) * 256 + o0] = v;
    }
}

extern "C" void kernel_launch(void* const* d_in, const int* in_sizes, int n_in,
                              void* d_out, int out_size, void* d_ws, size_t ws_size,
                              hipStream_t stream) {
    const float* xyz     = (const float*)d_in[0];
    const float* feature = (const float*)d_in[1];
    const float* new_xyz = (const float*)d_in[2];
    const int*   idx     = (const int*)  d_in[3];
    const float* weight  = (const float*)d_in[4];
    const float* conv_w  = (const float*)d_in[5];
    const float* conv_b  = (const float*)d_in[6];
    const float* mlp_w0  = (const float*)d_in[7];
    const float* mlp_b0  = (const float*)d_in[8];
    const float* mlp_w1  = (const float*)d_in[9];
    const float* mlp_b1  = (const float*)d_in[10];

    float* out    = (float*)d_out;
    float* out_rf = out + (size_t)B * M * 3;

    float* wsf = (float*)d_ws;
    __hip_bfloat16* xfh = (__hip_bfloat16*)wsf;  // 320000 bf16 = 160000 floats
    float* conv_wT = wsf + 160000;               // 13312 (208x64 zero-padded)
    float* xmid    = conv_wT + 13312;            // B*M*128 = 1048576, [col][c]
    float* w0T     = xmid + 1048576;             // 16384
    float* w1T     = w0T + 16384;                // 32768

    // A: prep
    {
        int total = 320000 + 13312 + 24576 + 16384 + 32768;   // 407040
        int blocks = (total + 255) / 256;
        prep_kernel<<<blocks, 256, 0, stream>>>(xyz, feature, new_xyz, conv_w,
                                                mlp_w0, mlp_w1,
                                                xfh, conv_wT, w0T, w1T, out);
    }
    // B: gather + conv
    {
        int blocks = S * B * M;                 // 16384
        gather_conv_kernel<<<blocks, 256, 0, stream>>>(idx, weight, new_xyz,
                                                       (const uint4*)xfh,
                                                       conv_wT, conv_b, xmid);
    }
    // C0: MLP0 (in-place on xmid)
    {
        int blocks = (B * M) / TC;              // 256
        mlp0_kernel<<<blocks, 256, 0, stream>>>(xmid, w0T, mlp_b0);
    }
    // C1: MLP1 + store
    {
        int blocks = (B * M) / TC;              // 256
        mlp1_kernel<<<blocks, 256, 0, stream>>>(xmid, w1T, mlp_b1, out_rf);
    }
}